// Round 3
// baseline (339.315 us; speedup 1.0000x reference)
//
#include <hip/hip_runtime.h>
#include <stdint.h>

// Problem constants (from reference)
#define BATCH   2048
#define IN_BITS 4096
#define N_IN    2048
#define N_ST    1024
#define N_OUT   1024
#define KBITS   14
#define MW      512   // 2^14 bits / 32 = words per packed mem row
#define SROW    96    // s_inp/o_inp packed row words: 3072 bits = 64 (h_in) + 32 (state/s_out)

// float4 counts per mem table
#define IM4 8388608   // N_IN * 16384 / 4
#define SM4 4194304   // N_ST * 16384 / 4
#define OM4 4194304
#define GS  524288    // grid-stride: 2048 blocks * 256 threads

typedef float f32x4 __attribute__((ext_vector_type(4)));
typedef int   i32x4 __attribute__((ext_vector_type(4)));

// ---------------------------------------------------------------------------
// Ballot-layout bit pack, grid-strided (unchanged from R2 for attribution).
// Layout per 256-bit chunk c -> words [8c..8c+7]:
//   word 8c + 2j + h holds bits of floats 256c + 4i + j, i in [32h,32h+32),
//   bit position i&31.
// Consumer remap for bit address a:
//   word = ((a>>5) & ~7) | ((a&3)<<1) | ((a>>7)&1);  shift = (a>>2)&31
__global__ __launch_bounds__(256) void pack_mem_all(const float* __restrict__ im,
                                                    const float* __restrict__ sm,
                                                    const float* __restrict__ om,
                                                    uint32_t* __restrict__ im_p,
                                                    uint32_t* __restrict__ sm_p,
                                                    uint32_t* __restrict__ om_p) {
    const int t = blockIdx.x * 256 + threadIdx.x;   // [0, GS)
    const int lane = threadIdx.x & 63;
#pragma unroll
    for (int c = 0; c < 32; ++c) {
        const float* s; uint32_t* d; int cl;
        if (c < 16)      { s = im; d = im_p; cl = c; }
        else if (c < 24) { s = sm; d = sm_p; cl = c - 16; }
        else             { s = om; d = om_p; cl = c - 24; }
        const long i = (long)cl * GS + t;            // float4 index within table
        f32x4 v = __builtin_nontemporal_load((const f32x4*)s + i);
        unsigned long long b0 = __ballot(v[0] == 1.0f);
        unsigned long long b1 = __ballot(v[1] == 1.0f);
        unsigned long long b2 = __ballot(v[2] == 1.0f);
        unsigned long long b3 = __ballot(v[3] == 1.0f);
        if (lane < 8) {
            unsigned long long bj = (lane & 4) ? ((lane & 2) ? b3 : b2)
                                               : ((lane & 2) ? b1 : b0);
            uint32_t w = (lane & 1) ? (uint32_t)(bj >> 32) : (uint32_t)bj;
            d[((i >> 6) << 3) + lane] = w;   // 8 lanes -> 32B contiguous
        }
    }
}

// Ballot-layout pack of input_bits (rows = 4096 bits = 16 chunks, 128 words).
__global__ __launch_bounds__(256) void pack_input(const int* __restrict__ src,
                                                  uint32_t* __restrict__ dst) {
    const int t = blockIdx.x * 256 + threadIdx.x;   // [0, GS)
    const int lane = threadIdx.x & 63;
#pragma unroll
    for (int c = 0; c < 4; ++c) {
        const long i = (long)c * GS + t;            // int4 index
        i32x4 v = __builtin_nontemporal_load((const i32x4*)src + i);
        unsigned long long b0 = __ballot(v[0] == 1);
        unsigned long long b1 = __ballot(v[1] == 1);
        unsigned long long b2 = __ballot(v[2] == 1);
        unsigned long long b3 = __ballot(v[3] == 1);
        if (lane < 8) {
            unsigned long long bj = (lane & 4) ? ((lane & 2) ? b3 : b2)
                                               : ((lane & 2) ? b1 : b0);
            uint32_t w = (lane & 1) ? (uint32_t)(bj >> 32) : (uint32_t)bj;
            dst[((i >> 6) << 3) + lane] = w;
        }
    }
}

// Coalesced pack of state_bits into buf_s at word offset 64, row stride SROW.
// LINEAR layout (matches ram_layer_t's linear word writes for words 0..63).
__global__ __launch_bounds__(256) void pack_state(const int4* __restrict__ src,
                                                  uint32_t* __restrict__ dst) {
    int t = blockIdx.x * 256 + threadIdx.x;  // one int4 per thread; row = 1024 bits
    int4 v = src[t];
    uint32_t nib = (uint32_t)(v.x == 1) | ((uint32_t)(v.y == 1) << 1) |
                   ((uint32_t)(v.z == 1) << 2) | ((uint32_t)(v.w == 1) << 3);
    int lane = threadIdx.x & 63;
    uint32_t w = nib << (4 * (lane & 7));
    w |= __shfl_xor(w, 1, 64);
    w |= __shfl_xor(w, 2, 64);
    w |= __shfl_xor(w, 4, 64);
    if ((lane & 7) == 0) {
        int g = t >> 3;          // global word index
        int r = g >> 5;          // 32 words per row
        int c = g & 31;
        dst[(long)r * SROW + 64 + c] = w;
    }
}

// ---------------------------------------------------------------------------
// TRANSPOSED RAM layer (R3 restructure).
// lane = batch (64 batches per block), wave = 16-neuron group, block-x = 64
// neurons. Why: the old lane=neuron form had (a) 14 scattered LDS reads/lane
// -> multiway bank conflicts, (b) wave-gathers touching 64 distinct mem rows
// (64 lines / 4KB L2 traffic per instruction), (c) per-lane conn loads.
// Now: conn/wd/sh are wave-uniform (SGPRs); LDS reads are
// lds[lane*ODD + wd] -> bank = (lane+wd)%32 -> exactly 2 lanes/bank = FREE;
// the gather reads ONE 2KB mem row per wave (~28 lines, uniform base);
// output accumulates 16 bits/lane -> one ushort store per 16 lookups.
// MODE 0: h_in -> dst0,dst1 words 0..63 (linear bit order, stride SROW)
// MODE 1: s_out -> dst0 words 64..95
// MODE 2: floats -> fout[b*N_OUT + n]
template <int SRCW, int MODE>
__global__ __launch_bounds__(256) void ram_layer_t(const uint32_t* __restrict__ src,
                                                   const int* __restrict__ conn,
                                                   const uint32_t* __restrict__ memp,
                                                   uint32_t* __restrict__ dst0,
                                                   uint32_t* __restrict__ dst1,
                                                   float* __restrict__ fout) {
    constexpr int LSTR = SRCW + 1;           // odd -> conflict-free column reads
    __shared__ uint32_t lds[64 * LSTR];
    const int tid = threadIdx.x;
    const int b0 = blockIdx.y * 64;

    // Stage 64 batch rows (contiguous in global: row stride == SRCW words).
    {
        const uint4* g = (const uint4*)(src + (long)b0 * SRCW);
        constexpr int NQ = 64 * SRCW / 4;
#pragma unroll
        for (int i = tid; i < NQ; i += 256) {
            uint4 v = g[i];
            int r = i / (SRCW / 4);
            int w = (i - r * (SRCW / 4)) * 4;
            uint32_t* p = &lds[r * LSTR + w];
            p[0] = v.x; p[1] = v.y; p[2] = v.z; p[3] = v.w;
        }
    }
    __syncthreads();

    const int lane = tid & 63;
    const int wave = __builtin_amdgcn_readfirstlane(tid >> 6);  // force SGPR
    const int nw0 = blockIdx.x * 64 + wave * 16;                // wave's 16 neurons
    const long b = b0 + lane;
    const uint32_t* row = lds + lane * LSTR;

    uint32_t acc = 0;
#pragma unroll 2
    for (int j = 0; j < 16; ++j) {
        const int n = nw0 + j;
        const int* cp = conn + n * KBITS;    // n wave-uniform -> s_load
        uint32_t addr = 0;
#pragma unroll
        for (int k = 0; k < KBITS; ++k) {
            int idx = cp[k];
            int wd, sh;
            if (SRCW == 128) {               // bits1 is ballot layout
                wd = ((idx >> 5) & ~7) | ((idx & 3) << 1) | ((idx >> 7) & 1);
                sh = (idx >> 2) & 31;
            } else {                         // SROW buffers are linear layout
                wd = idx >> 5;
                sh = idx & 31;
            }
            addr = (addr << 1) | ((row[wd] >> sh) & 1u);
        }
        // mem tables are ballot layout: remap bit address -> (word, shift)
        uint32_t mw = ((addr >> 5) & ~7u) | ((addr & 3u) << 1) | ((addr >> 7) & 1u);
        uint32_t bit = (memp[(long)n * MW + mw] >> ((addr >> 2) & 31u)) & 1u;
        if (MODE == 2) {
            fout[b * N_OUT + n] = (float)bit;
        } else {
            acc |= bit << j;
        }
    }
    if (MODE != 2) {
        // bit j of acc = neuron nw0+j at linear bit position 16*half + j
        const int woff = (MODE == 0 ? 0 : 64) + (nw0 >> 5);
        const int half = (nw0 >> 4) & 1;
        ((ushort*)(dst0 + b * SROW + woff))[half] = (ushort)acc;
        if (MODE == 0)
            ((ushort*)(dst1 + b * SROW + woff))[half] = (ushort)acc;
    }
}

// ---------------------------------------------------------------------------
extern "C" void kernel_launch(void* const* d_in, const int* in_sizes, int n_in,
                              void* d_out, int out_size, void* d_ws, size_t ws_size,
                              hipStream_t stream) {
    const int*   input_bits = (const int*)d_in[0];
    const int*   state_bits = (const int*)d_in[1];
    const int*   in_conn    = (const int*)d_in[2];
    const float* in_mem     = (const float*)d_in[3];
    const int*   st_conn    = (const int*)d_in[4];
    const float* st_mem     = (const float*)d_in[5];
    const int*   out_conn   = (const int*)d_in[6];
    const float* out_mem    = (const float*)d_in[7];
    float*       out        = (float*)d_out;

    // Workspace layout (all 256B-aligned):
    //   bits1 : [B][128] u32  = 1 MB   (packed input_bits, ballot layout)
    //   buf_s : [B][96]  u32  = 768 KB (s_inp bits: h_in | state, linear)
    //   buf_o : [B][96]  u32  = 768 KB (o_inp bits: h_in | s_out, linear)
    //   im_p  : [2048][512]   = 4 MB   (ballot layout)
    //   sm_p  : [1024][512]   = 2 MB   (ballot layout)
    //   om_p  : [1024][512]   = 2 MB   (ballot layout)
    char* ws = (char*)d_ws;
    uint32_t* bits1 = (uint32_t*)(ws);
    uint32_t* buf_s = (uint32_t*)(ws + 1048576);
    uint32_t* buf_o = (uint32_t*)(ws + 1048576 + 786432);
    uint32_t* im_p  = (uint32_t*)(ws + 1048576 + 2 * 786432);
    uint32_t* sm_p  = (uint32_t*)(ws + 1048576 + 2 * 786432 + 4194304);
    uint32_t* om_p  = (uint32_t*)(ws + 1048576 + 2 * 786432 + 4194304 + 2097152);

    // Bit-pack inputs (ballot layout; grid-strided for MLP).
    pack_input<<<2048, 256, 0, stream>>>(input_bits, bits1);
    pack_state<<<(BATCH * N_ST / 4) / 256, 256, 0, stream>>>((const int4*)state_bits, buf_s);
    pack_mem_all<<<2048, 256, 0, stream>>>(in_mem, st_mem, out_mem, im_p, sm_p, om_p);

    // Layer 1: input_bits -> h_in (into both buf_s and buf_o, words 0..63)
    ram_layer_t<128, 0><<<dim3(N_IN / 64, BATCH / 64), 256, 0, stream>>>(
        bits1, in_conn, im_p, buf_s, buf_o, nullptr);
    // Layer 2: s_inp -> s_out (into buf_o words 64..95)
    ram_layer_t<SROW, 1><<<dim3(N_ST / 64, BATCH / 64), 256, 0, stream>>>(
        buf_s, st_conn, sm_p, buf_o, nullptr, nullptr);
    // Layer 3: o_inp -> output floats
    ram_layer_t<SROW, 2><<<dim3(N_OUT / 64, BATCH / 64), 256, 0, stream>>>(
        buf_o, out_conn, om_p, nullptr, nullptr, out);
}